// Round 5
// baseline (594476.660 us; speedup 1.0000x reference)
//
#include <hip/hip_runtime.h>
#include <stdint.h>

#define HID 1024
#define NLAYERS 8
#define NLET 100
#define T_TOTAL 4096

typedef uint32_t u32x4 __attribute__((ext_vector_type(4)));
typedef uint32_t u32x2 __attribute__((ext_vector_type(2)));

// ---------- helpers ----------
__device__ __forceinline__ uint32_t f2bf(float f) {
    uint32_t u = __float_as_uint(f);
    return (u + 0x7FFFu + ((u >> 16) & 1u)) >> 16;
}
__device__ __forceinline__ float bflo(uint32_t p) { return __uint_as_float(p << 16); }
__device__ __forceinline__ float bfhi(uint32_t p) { return __uint_as_float(p & 0xFFFF0000u); }
__device__ __forceinline__ float sigm(float x) { return 1.0f / (1.0f + __expf(-x)); }
__device__ __forceinline__ float tanh_f(float x) {
    float xx = fminf(fmaxf(x, -15.0f), 15.0f);
    float e = __expf(2.0f * xx);
    return (e - 1.0f) / (e + 1.0f);
}

// ---- device-coherent (LLC) ops: sc0 sc1 ----
__device__ __forceinline__ void store_coh_x2(void* p, u32x2 d) {
    asm volatile("global_store_dwordx2 %0, %1, off sc0 sc1" ::"v"(p), "v"(d) : "memory");
}
__device__ __forceinline__ void load_coh_2x4(const void* p0, const void* p1, u32x4& a, u32x4& b) {
    asm volatile(
        "global_load_dwordx4 %0, %2, off sc0 sc1\n\t"
        "global_load_dwordx4 %1, %3, off sc0 sc1\n\t"
        "s_waitcnt vmcnt(0)"
        : "=v"(a), "=v"(b)
        : "v"(p0), "v"(p1)
        : "memory");
}
#define LOAD8(FLAGS, NAME)                                                                   \
    __device__ __forceinline__ void NAME(const char* p, u32x4& r0, u32x4& r1, u32x4& r2,     \
                                         u32x4& r3, u32x4& r4, u32x4& r5, u32x4& r6,         \
                                         u32x4& r7) {                                        \
        asm volatile("global_load_dwordx4 %0, %8, off " FLAGS "\n\t"                         \
                     "global_load_dwordx4 %1, %9, off " FLAGS "\n\t"                         \
                     "global_load_dwordx4 %2, %10, off " FLAGS "\n\t"                        \
                     "global_load_dwordx4 %3, %11, off " FLAGS "\n\t"                        \
                     "global_load_dwordx4 %4, %12, off " FLAGS "\n\t"                        \
                     "global_load_dwordx4 %5, %13, off " FLAGS "\n\t"                        \
                     "global_load_dwordx4 %6, %14, off " FLAGS "\n\t"                        \
                     "global_load_dwordx4 %7, %15, off " FLAGS "\n\t"                        \
                     "s_waitcnt vmcnt(0)"                                                    \
                     : "=v"(r0), "=v"(r1), "=v"(r2), "=v"(r3), "=v"(r4), "=v"(r5), "=v"(r6), \
                       "=v"(r7)                                                              \
                     : "v"(p), "v"(p + 1024), "v"(p + 2048), "v"(p + 3072), "v"(p + 4096),   \
                       "v"(p + 5120), "v"(p + 6144), "v"(p + 7168)                           \
                     : "memory");                                                            \
    }
LOAD8("sc0", load8_l2)        // XCD-L2 (bypass L1 only)
LOAD8("sc0 sc1", load8_coh)   // device-coherent (LLC)
#undef LOAD8
__device__ __forceinline__ void store_l2_x4(void* p, u32x4 d) {
    asm volatile("global_store_dwordx4 %0, %1, off sc0" ::"v"(p), "v"(d) : "memory");
}

// ---------- kernel 1: persistent stacked-LSTM scan, XCD-relay broadcast w/ fallback ----------
// 256 blocks x 512 threads (8 waves), 1 block/CU (VGPR-forced). Block b owns units
// {4b..4b+3}. Wave w: unit u=w&3, half=w>>2 computes layers half*4..half*4+3.
// Weights register-resident bf16 (160 regs/lane -> no spill at 256-VGPR cap).
//
// Broadcast protocol, step s = t*8+l+1 (all payloads are self-validating {h,step} 8B pairs;
// unit-linear layout: pair g=global unit, chunk = producer block = 4 pairs = 32B):
//   pre-A : active waves compute; lane0 publishes {h,s} to gchunks[par] (LLC).
//   A..B  : relay block (1/XCD, elected via XCC_ID+ticket; pure optimization):
//             idle-half wave q polls gchunks[par] chunks q*64+lane (LLC) until tags==s,
//             then copies the 32B verbatim to localbuf (sc0 -> XCD L2). Single-buffered:
//             overwrite for s+1 can only happen after every block consumed s (publish of
//             s+1 requires h(s)).
//           consumer wave (idle-half wave in normal blocks; active-half in relay block):
//             polls localbuf (sc0, served by own XCD L2) <=24 tries, else falls back to
//             polling gchunks[par] at LLC (with s_sleep to avoid flood). Stale-tag safety:
//             tags are monotone within a launch; 0xAA poison never matches.
//   B     : h_lds holds h(s).
__global__ void __launch_bounds__(512, 1)
lstm_persistent(const float* __restrict__ website, const float* __restrict__ payload,
                const float* __restrict__ W_ih, const float* __restrict__ W_hh,
                const float* __restrict__ b_ih, const float* __restrict__ b_hh,
                char* ws, float* c_out, int use_relay) {
    __shared__ __align__(16) float h_lds[HID];
    __shared__ float c_lds[4];
    __shared__ int info_lds[2];  // [xcc, is_relay]

    const int tid = threadIdx.x;  // 0..511
    const int b = blockIdx.x;     // 0..255
    const int w = tid >> 6;       // wave 0..7
    const int lane = tid & 63;
    const int u = w & 3;          // unit within block / relay quarter
    const int half = w >> 2;      // 0: layers 0-3, 1: layers 4-7
    const int k = b * 4 + u;      // global hidden unit

    uint32_t* claim = (uint32_t*)ws;   // 8 u32 @0 (zeroed each launch)
    char* gchunks = ws + 4096;         // [par*256 + prod]*32B, ends 20480
    char* localbuf = ws + 24576;       // [xcc*256 + prod]*32B, ends 90112 (c_out @20480)

    // ---- relay election (once): one relay block per XCD (best-effort) ----
    if (tid == 0) {
        uint32_t xcc = 0;
        asm volatile("s_getreg_b32 %0, hwreg(HW_REG_XCC_ID)" : "=s"(xcc));
        xcc &= 7u;
        uint32_t ticket = use_relay ? atomicAdd(&claim[xcc], 1u) : 1u;
        info_lds[0] = (int)xcc;
        info_lds[1] = (ticket == 0u) ? 1 : 0;
    }

    // ---- one-time: pack this wave's weights into registers as bf16 pairs ----
    uint32_t wh[4][4][8];  // [local layer][gate][pair p] -> h-cols (2L+128p, +1)
    uint32_t wx[4][4];
    float bias[4][4];
#pragma unroll
    for (int ll = 0; ll < 4; ++ll) {
        const int l = half * 4 + ll;
#pragma unroll
        for (int g = 0; g < 4; ++g) {
            const int row = 1024 * g + k;
            const float* src = W_hh + ((size_t)(l * 4096 + row)) * 1024;
#pragma unroll
            for (int p = 0; p < 8; ++p) {
                const int c0 = 2 * lane + 128 * p;
                wh[ll][g][p] = f2bf(src[c0]) | (f2bf(src[c0 + 1]) << 16);
            }
            if (lane < 50) {
                const float* sx = W_ih + ((size_t)(l * 4096 + row)) * NLET + 2 * lane;
                wx[ll][g] = f2bf(sx[0]) | (f2bf(sx[1]) << 16);
            } else {
                wx[ll][g] = 0u;
            }
            bias[ll][g] = b_ih[l * 4096 + row] + b_hh[l * 4096 + row];
        }
    }

    if (tid < 256) ((float4*)h_lds)[tid] = make_float4(0.f, 0.f, 0.f, 0.f);
    if (tid < 4) c_lds[tid] = 0.0f;
    __syncthreads();
    const int xcc = info_lds[0];
    const int is_relay = info_lds[1];
    char* mylocal = localbuf + (size_t)xcc * 8192;

    for (int t = 0; t < T_TOTAL; ++t) {
        float x0 = 0.f, x1 = 0.f;
        if (lane < 50) {
            const float* xp = (t < 2048) ? (website + (size_t)t * NLET)
                                         : (payload + (size_t)(t - 2048) * NLET);
            float2 xv = *(const float2*)&xp[2 * lane];
            x0 = xv.x;
            x1 = xv.y;
        }
#pragma unroll
        for (int l = 0; l < NLAYERS; ++l) {
            const int s = t * NLAYERS + l + 1;  // step being produced
            const int par = s & 1;
            const int hl = l >> 2;
            const uint32_t su = (uint32_t)s;

            if (hl == half) {
                const int ll = l & 3;
                float2 hv[8];
#pragma unroll
                for (int p = 0; p < 8; ++p) hv[p] = *(const float2*)&h_lds[2 * lane + 128 * p];
                float acc0 = 0.f, acc1 = 0.f, acc2 = 0.f, acc3 = 0.f;
#pragma unroll
                for (int p = 0; p < 8; ++p) {
                    const float hA = hv[p].x, hB = hv[p].y;
                    uint32_t ww;
                    ww = wh[ll][0][p]; acc0 = fmaf(bflo(ww), hA, acc0); acc0 = fmaf(bfhi(ww), hB, acc0);
                    ww = wh[ll][1][p]; acc1 = fmaf(bflo(ww), hA, acc1); acc1 = fmaf(bfhi(ww), hB, acc1);
                    ww = wh[ll][2][p]; acc2 = fmaf(bflo(ww), hA, acc2); acc2 = fmaf(bfhi(ww), hB, acc2);
                    ww = wh[ll][3][p]; acc3 = fmaf(bflo(ww), hA, acc3); acc3 = fmaf(bfhi(ww), hB, acc3);
                }
                {
                    uint32_t ww;
                    ww = wx[ll][0]; acc0 = fmaf(bflo(ww), x0, acc0); acc0 = fmaf(bfhi(ww), x1, acc0);
                    ww = wx[ll][1]; acc1 = fmaf(bflo(ww), x0, acc1); acc1 = fmaf(bfhi(ww), x1, acc1);
                    ww = wx[ll][2]; acc2 = fmaf(bflo(ww), x0, acc2); acc2 = fmaf(bfhi(ww), x1, acc2);
                    ww = wx[ll][3]; acc3 = fmaf(bflo(ww), x0, acc3); acc3 = fmaf(bfhi(ww), x1, acc3);
                }
#pragma unroll
                for (int mm = 32; mm > 0; mm >>= 1) {
                    acc0 += __shfl_xor(acc0, mm, 64);
                    acc1 += __shfl_xor(acc1, mm, 64);
                    acc2 += __shfl_xor(acc2, mm, 64);
                    acc3 += __shfl_xor(acc3, mm, 64);
                }
                const float gi = sigm(acc0 + bias[ll][0]);
                const float gf = sigm(acc1 + bias[ll][1]);
                const float gg = tanh_f(acc2 + bias[ll][2]);
                const float go = sigm(acc3 + bias[ll][3]);
                const float cn = fmaf(gf, c_lds[u], gi * gg);
                const float hn = go * tanh_f(cn);
                if (lane == 0) {
                    c_lds[u] = cn;
                    u32x2 d;
                    d.x = __float_as_uint(hn);
                    d.y = su;
                    store_coh_x2(gchunks + ((size_t)(par * 256 + b)) * 32 + u * 8, d);
                }
            }
            __syncthreads();  // A

            if (is_relay && hl != half) {
                // ---- relay: idle-half wave u copies validated chunks LLC -> XCD L2 ----
                const char* gp = gchunks + ((size_t)(par * 256 + u * 64 + lane)) * 32;
                u32x4 a0, a1;
                bool done = false;
                do {
                    load_coh_2x4(gp, gp + 16, a0, a1);
                    done = (a0.y == su) && (a0.w == su) && (a1.y == su) && (a1.w == su);
                } while (!done);
                char* lp = mylocal + ((size_t)(u * 64 + lane)) * 32;
                store_l2_x4(lp, a0);
                store_l2_x4(lp + 16, a1);
            }
            // consumer wave: idle-half wave 4*(1-hl) normally; active wave 4*hl in relay block
            if (w == (is_relay ? 4 * hl : 4 * (1 - hl))) {
                u32x4 r0, r1, r2, r3, r4, r5, r6, r7;
                bool got = false;
                const char* lp = mylocal + 16 * lane;
                for (int tries = 0; tries < 24; ++tries) {
                    load8_l2(lp, r0, r1, r2, r3, r4, r5, r6, r7);
                    bool ok = (r0.y == su) && (r0.w == su) && (r1.y == su) && (r1.w == su) &&
                              (r2.y == su) && (r2.w == su) && (r3.y == su) && (r3.w == su) &&
                              (r4.y == su) && (r4.w == su) && (r5.y == su) && (r5.w == su) &&
                              (r6.y == su) && (r6.w == su) && (r7.y == su) && (r7.w == su);
                    if (__all(ok)) { got = true; break; }
                }
                if (!got) {
                    const char* gp = gchunks + (size_t)par * 8192 + 16 * lane;
                    for (;;) {
                        load8_coh(gp, r0, r1, r2, r3, r4, r5, r6, r7);
                        bool ok = (r0.y == su) && (r0.w == su) && (r1.y == su) && (r1.w == su) &&
                                  (r2.y == su) && (r2.w == su) && (r3.y == su) && (r3.w == su) &&
                                  (r4.y == su) && (r4.w == su) && (r5.y == su) && (r5.w == su) &&
                                  (r6.y == su) && (r6.w == su) && (r7.y == su) && (r7.w == su);
                        if (__all(ok)) break;
                        __builtin_amdgcn_s_sleep(8);
                    }
                }
                // chunk p covers global units (2*lane+128p, +1): h in .x / .z
                float2* hd = (float2*)&h_lds[2 * lane];
                hd[0 * 64] = make_float2(__uint_as_float(r0.x), __uint_as_float(r0.z));
                hd[1 * 64] = make_float2(__uint_as_float(r1.x), __uint_as_float(r1.z));
                hd[2 * 64] = make_float2(__uint_as_float(r2.x), __uint_as_float(r2.z));
                hd[3 * 64] = make_float2(__uint_as_float(r3.x), __uint_as_float(r3.z));
                hd[4 * 64] = make_float2(__uint_as_float(r4.x), __uint_as_float(r4.z));
                hd[5 * 64] = make_float2(__uint_as_float(r5.x), __uint_as_float(r5.z));
                hd[6 * 64] = make_float2(__uint_as_float(r6.x), __uint_as_float(r6.z));
                hd[7 * 64] = make_float2(__uint_as_float(r7.x), __uint_as_float(r7.z));
            }
            __syncthreads();  // B: h_lds holds h(s)
        }
    }
    if (tid < 4) c_out[b * 4 + tid] = c_lds[tid];
}

// ---------- kernel 2: head ----------
__global__ void head_kernel(const float* __restrict__ c_out, const float* __restrict__ W_lin,
                            const float* __restrict__ b_lin, const float* __restrict__ W_out,
                            const float* __restrict__ b_out, float* out) {
    const int lane = threadIdx.x;  // one wave
    float cv[16];
    const float4* cp = (const float4*)(c_out + lane * 16);
#pragma unroll
    for (int q = 0; q < 4; ++q) {
        float4 v = cp[q];
        cv[4 * q + 0] = v.x;
        cv[4 * q + 1] = v.y;
        cv[4 * q + 2] = v.z;
        cv[4 * q + 3] = v.w;
    }
    float fsum = 0.f;
#pragma unroll
    for (int i = 0; i < 16; ++i) {
        const float* wr = W_lin + (size_t)i * HID + lane * 16;
        float a = 0.f;
#pragma unroll
        for (int m = 0; m < 16; ++m) a = fmaf(wr[m], cv[m], a);
#pragma unroll
        for (int mm = 32; mm > 0; mm >>= 1) a += __shfl_xor(a, mm, 64);
        fsum = fmaf(W_out[i], a + b_lin[i], fsum);
    }
    if (lane == 0) out[0] = sigm(fsum + b_out[0]);
}

extern "C" void kernel_launch(void* const* d_in, const int* in_sizes, int n_in, void* d_out,
                              int out_size, void* d_ws, size_t ws_size, hipStream_t stream) {
    (void)in_sizes; (void)n_in; (void)out_size;
    const float* website = (const float*)d_in[0];
    const float* payload = (const float*)d_in[1];
    const float* W_ih = (const float*)d_in[2];
    const float* W_hh = (const float*)d_in[3];
    const float* b_ih = (const float*)d_in[4];
    const float* b_hh = (const float*)d_in[5];
    const float* W_lin = (const float*)d_in[6];
    const float* b_lin = (const float*)d_in[7];
    const float* W_out = (const float*)d_in[8];
    const float* b_out = (const float*)d_in[9];

    char* ws = (char*)d_ws;
    float* c_out = (float*)(ws + 20480);                 // 4 KB @ 20480
    const int use_relay = (ws_size >= 90112) ? 1 : 0;    // localbuf @24576..90112

    hipMemsetAsync(ws, 0, 4096, stream);  // election counters
    lstm_persistent<<<256, 512, 0, stream>>>(website, payload, W_ih, W_hh, b_ih, b_hh, ws,
                                             c_out, use_relay);
    head_kernel<<<1, 64, 0, stream>>>(c_out, W_lin, b_lin, W_out, b_out, (float*)d_out);
}